// Round 21
// baseline (314.608 us; speedup 1.0000x reference)
//
#include <hip/hip_runtime.h>

#define NCOLS 256
#define NP    128
#define DD    256

typedef _Float16 half2 __attribute__((ext_vector_type(2)));
typedef _Float16 half4 __attribute__((ext_vector_type(4)));
typedef _Float16 half8 __attribute__((ext_vector_type(8)));
typedef float    f32x4 __attribute__((ext_vector_type(4)));

// gfx950 spellings (both compile-verified in-session: R1/R3)
#define MFMA16(a,b,c) __builtin_amdgcn_mfma_f32_16x16x16f16(a,b,c,0,0,0)
#define MFMA32(a,b,c) __builtin_amdgcn_mfma_f32_16x16x32_f16(a,b,c,0,0,0)

// ---- workspace layout (bytes) ----
#define WS_COL_LN   0          // f32 [256][256]  LN(emb_column)   (for k_prep2)
#define WS_BASE     393216     // f32 [128][256]  base (prompt-side xp part)
#define WS_BLOG     524288     // f32 [128][256]  base_logits
#define WS_CW16     655360     // f16 CW in K=32 MFMA A-fragment order
#define WS_WB16     786432     // half2 [256][256] {w,b} interleaved feature emb

// ---- main LDS (bytes) ----
// x dbuf 2x1K @0 | sm_m 1K @2048 | sm_l 1K @3072 |
// region @4096: phase1 CW 128 KB; phase2 reuse: P 64 KB @4096,
//               xe dbuf 2x32 KB @69632/@102400 (over dead CW upper half)
#define LDS_CWP   4096
#define LDS_XE0   69632
#define LDS_XE1   102400
#define SMEM_MAIN 135168       // 1 block/CU; 16 waves = 4/SIMD

// ============================ prep kernel 1 ============================
// blocks 0..255  : col_ln row n inline -> ws + CW row n (K=32 frag order)
// blocks 256..383: prompt row-LN inline -> base row p
// blocks 384..511: half2 {w,b} interleave of feature emb weights
__global__ __launch_bounds__(256) void k_prep1(
    const float* __restrict__ emb_column, const float* __restrict__ emb_prompt,
    const float* __restrict__ ln_col_g, const float* __restrict__ ln_col_b,
    const float* __restrict__ ln_prompt_g, const float* __restrict__ ln_prompt_b,
    const float* __restrict__ few, const float* __restrict__ feb,
    const float* __restrict__ diw, const float* __restrict__ dib,
    char* __restrict__ ws)
{
    __shared__ float red[10];
    __shared__ float rowv[DD];
    int blk = blockIdx.x, tid = threadIdx.x;

    if (blk < 384) {
        bool isCol = blk < 256;
        int r = isCol ? blk : blk - 256;
        const float* src = (isCol ? emb_column : emb_prompt) + r*DD;
        const float* g   = isCol ? ln_col_g : ln_prompt_g;
        const float* bb  = isCol ? ln_col_b : ln_prompt_b;

        float v = src[tid];
        float s = v, q = v*v;
        #pragma unroll
        for (int off = 32; off; off >>= 1) { s += __shfl_xor(s, off); q += __shfl_xor(q, off); }
        int wid = tid >> 6, lane = tid & 63;
        if (lane == 0) { red[wid] = s; red[4+wid] = q; }
        __syncthreads();
        if (tid == 0) {
            float S = red[0]+red[1]+red[2]+red[3];
            float Q = red[4]+red[5]+red[6]+red[7];
            float mu = S * (1.0f/DD);
            float var = Q * (1.0f/DD) - mu*mu;
            red[8] = mu; red[9] = rsqrtf(var + 1e-5f);
        }
        __syncthreads();
        float ln = (v - red[8]) * red[9] * g[tid] + bb[tid];
        rowv[tid] = ln;
        if (isCol) ((float*)(ws + WS_COL_LN))[r*DD + tid] = ln;  // k_prep2 input
        __syncthreads();

        if (isCol) {
            int n = r;
            float acc = 0.f;
            #pragma unroll 4
            for (int d = 0; d < DD; ++d) acc += rowv[d] * diw[d*512 + 256 + tid];
            int nt = n >> 4, lr = n & 15;
            int kc32 = tid >> 5, lq = (tid >> 3) & 3, jj = tid & 7;
            ((_Float16*)(ws + WS_CW16))[(kc32*16 + nt)*512 + (lq*16 + lr)*8 + jj] = (_Float16)acc;
        } else {
            int p = r;
            float acc = 0.f;
            #pragma unroll 4
            for (int k = 0; k < DD; ++k) acc += rowv[k] * diw[tid*512 + k];
            ((float*)(ws + WS_BASE))[p*DD + tid] = acc + dib[tid] + emb_prompt[p*DD + tid];
        }
    } else {
        int base = (blk - 384) * 512;
        half2* wb = (half2*)(ws + WS_WB16);
        #pragma unroll
        for (int j = 0; j < 2; ++j) {
            int idx = base + j*256 + tid;      // 0..65535
            half2 h; h[0] = (_Float16)few[idx]; h[1] = (_Float16)feb[idx];
            wb[idx] = h;
        }
    }
}

// ============================ prep kernel 2 ============================
// base_logits[p][n] = sum_d base[p][d] * col_ln[n][d]
__global__ __launch_bounds__(256) void k_prep2(char* __restrict__ ws)
{
    __shared__ float bs[DD];
    int p = blockIdx.x, n = threadIdx.x;
    const float* base   = (const float*)(ws + WS_BASE);
    const float* col_ln = (const float*)(ws + WS_COL_LN);
    bs[n] = base[p*DD + n];
    __syncthreads();
    float acc = 0.f;
    #pragma unroll 4
    for (int d = 0; d < DD; ++d) acc += bs[d] * col_ln[n*DD + d];
    ((float*)(ws + WS_BLOG))[p*DD + n] = acc;
}

// ============================ main kernel ============================
// PERSISTENT: grid 256 (1 block/CU), each block loops 4 batches
// b = bid + 256*it. Per-iteration body = R20's measured-best form.
// Cross-batch prefetch: pf (prev f16 frags) reloaded IN PLACE right
// after P1 (its last use) for the next batch -> HBM latency hides under
// softmax+P2 (~30us). Next x row -> 1KB LDS double buffer. CW re-staged
// per iteration from L2 (P overwrites it). gcc/bcc/blog hoisted.
__global__ __launch_bounds__(1024) void trompt_main(
    const float* __restrict__ x, const float* __restrict__ prev,
    const float* __restrict__ expand_w, const float* __restrict__ expand_b,
    const float* __restrict__ ln_emb_g, const float* __restrict__ ln_emb_b,
    const char* __restrict__ ws, float* __restrict__ out)
{
    extern __shared__ char smem[];
    float* x_sA = (float*)(smem);
    float* x_sB = (float*)(smem + 1024);
    float* sm_m = (float*)(smem + 2048);
    float* sm_l = (float*)(smem + 3072);
    char*  cwP  = smem + LDS_CWP;        // CW (P1) then P (P2)
    char*  xe0  = smem + LDS_XE0;
    char*  xe1  = smem + LDS_XE1;

    const char*  cwbase = ws + WS_CW16;
    const half2* WB     = (const half2*)(ws + WS_WB16);

    int bid = blockIdx.x;
    int tid = threadIdx.x;
    int w = tid >> 6, l = tid & 63, lq = l >> 4, lr = l & 15;
    int pt = w >> 1, h = w & 1;
    int p  = 16*pt + lr;
    int pswz = (p & 7) << 4;
    int kc2w = w >> 2, lq2 = w & 3;

    // hoisted constants
    float gcc[4], bcc[4];
    #pragma unroll
    for (int cc = 0; cc < 4; ++cc) {
        gcc[cc] = ln_emb_g[l + 64*cc];
        bcc[cc] = ln_emb_b[l + 64*cc];
    }
    const float* blrow = (const float*)(ws + WS_BLOG) + (size_t)p*DD + 4*lq;

    // pf loader: prev row of batch bb -> f16 K=32 B-fragments (32 VGPRs)
    half8 pf[8];
    auto load_pf = [&](int bb) {
        const float* prow = prev + ((size_t)bb*NP + p)*DD + 8*lq;
        #pragma unroll
        for (int kc = 0; kc < 8; ++kc) {
            f32x4 v0 = *(const f32x4*)(prow + 32*kc);
            f32x4 v1 = *(const f32x4*)(prow + 32*kc + 4);
            half8 hh;
            #pragma unroll
            for (int j = 0; j < 4; ++j) { hh[j] = (_Float16)v0[j]; hh[4+j] = (_Float16)v1[j]; }
            pf[kc] = hh;
        }
    };

    // xe chunk compute: 64 n-rows -> f16 K=16 fragment buffer; 4 rows/wave.
    auto compute_xe = [&](const float* xs, int c, char* xebuf) {
        float vj[4][4];
        #pragma unroll
        for (int j = 0; j < 4; ++j) {
            int n = c*64 + 16*kc2w + 4*lq2 + j;
            float xv = xs[n];
            const half2* wbrow = WB + n*DD;
            float ss = 0.f, qq = 0.f;
            #pragma unroll
            for (int cc = 0; cc < 4; ++cc) {
                half2 pp = wbrow[l + 64*cc];
                float e = fmaf(xv, (float)pp[0], (float)pp[1]);
                e = e > 0.f ? e : 0.f;
                vj[j][cc] = e; ss += e; qq += e*e;
            }
            #pragma unroll
            for (int off = 32; off; off >>= 1) { ss += __shfl_xor(ss, off); qq += __shfl_xor(qq, off); }
            float mu = ss * (1.0f/DD);
            float rs = rsqrtf(qq*(1.0f/DD) - mu*mu + 1e-5f);
            #pragma unroll
            for (int cc = 0; cc < 4; ++cc)
                vj[j][cc] = (vj[j][cc]-mu)*rs*gcc[cc] + bcc[cc];
        }
        #pragma unroll
        for (int cc = 0; cc < 4; ++cc) {
            int dt = 4*cc + (l >> 4);
            half4 hh;
            #pragma unroll
            for (int j = 0; j < 4; ++j) hh[j] = (_Float16)vj[j][cc];
            *(half4*)(xebuf + (((kc2w*16 + dt)*64) + lq2*16 + lr)*8) = hh;
        }
    };

    // prologue: batch bid
    if (tid < 256) x_sA[tid] = x[bid*NCOLS + tid];
    load_pf(bid);

    #pragma unroll 1
    for (int it = 0; it < 4; ++it) {
        int b = bid + 256*it;
        const float* xs  = (it & 1) ? x_sB : x_sA;
        float*       xsn = (it & 1) ? x_sA : x_sB;

        __syncthreads();             // prev iter PV/epilogue done; P dead; xs ready

        // stage CW: 1024 thr x 8 x 16B = 128 KB from L2
        #pragma unroll
        for (int i = 0; i < 8; ++i) {
            int u = tid + 1024*i;
            *(uint4*)(cwP + u*16) = *(const uint4*)(cwbase + u*16);
        }

        // C-init from base_logits: acc[a] <-> n-tile nt = 8h + a
        f32x4 acc[8];
        #pragma unroll
        for (int a = 0; a < 8; ++a) acc[a] = *(const f32x4*)(blrow + 16*(8*h + a));

        __syncthreads();             // CW ready

        // ---- Phase 1: logits, barrier-free 64x(b128+MFMA32) stretch ----
        {
            const char* cwl = cwP + (size_t)(8*h)*1024 + l*16;
            #pragma unroll
            for (int kc = 0; kc < 8; ++kc) {
                const char* fb = cwl + (size_t)kc*16384;
                half8 bp = pf[kc];
                #pragma unroll
                for (int a = 0; a < 8; ++a)
                    acc[a] = MFMA32(*(const half8*)(fb + a*1024), bp, acc[a]);
            }
        }

        // ---- cross-batch prefetch: pf dead -> reload for next batch ----
        if (it < 3) {
            load_pf(b + 256);
            if (tid < 256) xsn[tid] = x[(b + 256)*NCOLS + tid];
        }

        // ---- softmax, single barrier: exp with LOCAL half-max ----
        float mh = -1e30f;
        #pragma unroll
        for (int a = 0; a < 8; ++a)
            #pragma unroll
            for (int r = 0; r < 4; ++r) mh = fmaxf(mh, acc[a][r]);
        mh = fmaxf(mh, __shfl_xor(mh, 16));
        mh = fmaxf(mh, __shfl_xor(mh, 32));

        float sh = 0.f;
        #pragma unroll
        for (int a = 0; a < 8; ++a)
            #pragma unroll
            for (int r = 0; r < 4; ++r) { float e = __expf(acc[a][r] - mh); acc[a][r] = e; sh += e; }
        sh += __shfl_xor(sh, 16);
        sh += __shfl_xor(sh, 32);

        if (lq == 0) { sm_m[h*128 + p] = mh; sm_l[h*128 + p] = sh; }
        __syncthreads();             // publish (m,s); also: all CW reads done
        float mo = sm_m[(1 ^ h)*128 + p];
        float so = sm_l[(1 ^ h)*128 + p];
        float M  = fmaxf(mh, mo);
        float eh = __expf(mh - M), eo = __expf(mo - M);
        float fac = eh / (sh*eh + so*eo);

        // ---- write normalized P (f16) over dead CW region, swizzled ----
        #pragma unroll
        for (int a = 0; a < 8; ++a) {
            int nb = (8*h + a)*32 + lq*8;    // byte offset of n*2 within row
            half4 hh;
            #pragma unroll
            for (int r = 0; r < 4; ++r) hh[r] = (_Float16)(acc[a][r] * fac);
            *(half4*)(cwP + p*512 + (nb ^ pswz)) = hh;
        }

        compute_xe(xs, 0, xe0);

        f32x4 acc_v[8];              // 16p x 128d: d = 128h + 16dtl + 4lq + r
        #pragma unroll
        for (int dtl = 0; dtl < 8; ++dtl) acc_v[dtl] = (f32x4){0.f,0.f,0.f,0.f};

        __syncthreads();             // P + xe0 complete

        for (int c = 0; c < 4; ++c) {
            char* xec = (c & 1) ? xe1 : xe0;
            char* xen = (c & 1) ? xe0 : xe1;

            // P B-fragments for this chunk (ds_read, swizzled)
            half4 bp[4];
            #pragma unroll
            for (int kc2 = 0; kc2 < 4; ++kc2)
                bp[kc2] = *(const half4*)(cwP + p*512 + ((c*128 + kc2*32 + lq*8) ^ pswz));

            if (c < 3) compute_xe(xs, c+1, xen);

            const char* xel = xec + l*8;
            #pragma unroll
            for (int kc2 = 0; kc2 < 4; ++kc2) {
                const char* xb = xel + (size_t)(kc2*16 + 8*h)*512;
                half4 bpc = bp[kc2];
                #pragma unroll
                for (int dtl = 0; dtl < 8; ++dtl)
                    acc_v[dtl] = MFMA16(*(const half4*)(xb + dtl*512), bpc, acc_v[dtl]);
            }

            if (c < 3) __syncthreads();
        }

        // epilogue: out = V*sw + sb (P pre-normalized); d-half per wave
        {
            float sw = 1.0f + expand_w[p];
            float sb = expand_b[p];
            float* orow = out + ((size_t)b*NP + p)*DD + 128*h + 4*lq;
            #pragma unroll
            for (int dtl = 0; dtl < 8; ++dtl) {
                f32x4 v = acc_v[dtl];
                #pragma unroll
                for (int r = 0; r < 4; ++r) v[r] = v[r]*sw + sb;
                *(f32x4*)(orow + 16*dtl) = v;
            }
        }
    }
}

// ============================ launcher ============================
extern "C" void kernel_launch(void* const* d_in, const int* in_sizes, int n_in,
                              void* d_out, int out_size, void* d_ws, size_t ws_size,
                              hipStream_t stream) {
    (void)in_sizes; (void)n_in; (void)out_size; (void)ws_size;
    const float* x           = (const float*)d_in[0];
    const float* prev        = (const float*)d_in[1];
    const float* few         = (const float*)d_in[2];
    const float* feb         = (const float*)d_in[3];
    const float* ln_emb_g    = (const float*)d_in[4];
    const float* ln_emb_b    = (const float*)d_in[5];
    const float* ln_col_g    = (const float*)d_in[6];
    const float* ln_col_b    = (const float*)d_in[7];
    const float* ln_prompt_g = (const float*)d_in[8];
    const float* ln_prompt_b = (const float*)d_in[9];
    const float* diw         = (const float*)d_in[10];
    const float* dib         = (const float*)d_in[11];
    const float* emb_column  = (const float*)d_in[12];
    const float* emb_prompt  = (const float*)d_in[13];
    const float* expand_w    = (const float*)d_in[14];
    const float* expand_b    = (const float*)d_in[15];
    char* ws = (char*)d_ws;
    float* out = (float*)d_out;

    k_prep1<<<512, 256, 0, stream>>>(emb_column, emb_prompt, ln_col_g, ln_col_b,
                                     ln_prompt_g, ln_prompt_b, few, feb,
                                     diw, dib, ws);
    k_prep2<<<128, 256, 0, stream>>>(ws);

    (void)hipFuncSetAttribute(reinterpret_cast<const void*>(trompt_main),
                              hipFuncAttributeMaxDynamicSharedMemorySize, SMEM_MAIN);
    trompt_main<<<256, 1024, SMEM_MAIN, stream>>>(x, prev, expand_w, expand_b,
                                                  ln_emb_g, ln_emb_b, ws, out);
}

// Round 22
// 181.177 us; speedup vs baseline: 1.7365x; 1.7365x over previous
//
#include <hip/hip_runtime.h>

#define NCOLS 256
#define NP    128
#define DD    256

typedef _Float16 half2 __attribute__((ext_vector_type(2)));
typedef _Float16 half4 __attribute__((ext_vector_type(4)));
typedef _Float16 half8 __attribute__((ext_vector_type(8)));
typedef float    f32x4 __attribute__((ext_vector_type(4)));

// gfx950 spellings (both compile-verified in-session: R1/R3)
#define MFMA16(a,b,c) __builtin_amdgcn_mfma_f32_16x16x16f16(a,b,c,0,0,0)
#define MFMA32(a,b,c) __builtin_amdgcn_mfma_f32_16x16x32_f16(a,b,c,0,0,0)

// ---- workspace layout (bytes) ----
#define WS_COL_LN   0          // f32 [256][256]  LN(emb_column)   (for k_prep2)
#define WS_BASE     393216     // f32 [128][256]  base (prompt-side xp part)
#define WS_BLOG     524288     // f32 [128][256]  base_logits
#define WS_CW16     655360     // f16 CW in K=32 MFMA A-fragment order
#define WS_WB16     786432     // half2 [256][256] {w,b} interleaved feature emb

// ---- main LDS (bytes) ----
// x_s 1K @0 | sm_m 1K @1024 | sm_l 1K @2048 |
// region @3072: phase1 CW 128 KB; phase2 reuse: P 64 KB @3072,
//               xe dbuf 2x32 KB @68608/@101376 (overlaps dead CW upper half)
#define LDS_CWP   3072
#define LDS_XE0   68608
#define LDS_XE1   101376
#define SMEM_MAIN 134144       // 1 block/CU; 16 waves = 4/SIMD

// ============================ prep kernel 1 ============================
// blocks 0..255  : col_ln row n inline -> ws + CW row n (K=32 frag order)
// blocks 256..383: prompt row-LN inline -> base row p
// blocks 384..511: half2 {w,b} interleave of feature emb weights
__global__ __launch_bounds__(256) void k_prep1(
    const float* __restrict__ emb_column, const float* __restrict__ emb_prompt,
    const float* __restrict__ ln_col_g, const float* __restrict__ ln_col_b,
    const float* __restrict__ ln_prompt_g, const float* __restrict__ ln_prompt_b,
    const float* __restrict__ few, const float* __restrict__ feb,
    const float* __restrict__ diw, const float* __restrict__ dib,
    char* __restrict__ ws)
{
    __shared__ float red[10];
    __shared__ float rowv[DD];
    int blk = blockIdx.x, tid = threadIdx.x;

    if (blk < 384) {
        bool isCol = blk < 256;
        int r = isCol ? blk : blk - 256;
        const float* src = (isCol ? emb_column : emb_prompt) + r*DD;
        const float* g   = isCol ? ln_col_g : ln_prompt_g;
        const float* bb  = isCol ? ln_col_b : ln_prompt_b;

        float v = src[tid];
        float s = v, q = v*v;
        #pragma unroll
        for (int off = 32; off; off >>= 1) { s += __shfl_xor(s, off); q += __shfl_xor(q, off); }
        int wid = tid >> 6, lane = tid & 63;
        if (lane == 0) { red[wid] = s; red[4+wid] = q; }
        __syncthreads();
        if (tid == 0) {
            float S = red[0]+red[1]+red[2]+red[3];
            float Q = red[4]+red[5]+red[6]+red[7];
            float mu = S * (1.0f/DD);
            float var = Q * (1.0f/DD) - mu*mu;
            red[8] = mu; red[9] = rsqrtf(var + 1e-5f);
        }
        __syncthreads();
        float ln = (v - red[8]) * red[9] * g[tid] + bb[tid];
        rowv[tid] = ln;
        if (isCol) ((float*)(ws + WS_COL_LN))[r*DD + tid] = ln;  // k_prep2 input
        __syncthreads();

        if (isCol) {
            int n = r;
            float acc = 0.f;
            #pragma unroll 4
            for (int d = 0; d < DD; ++d) acc += rowv[d] * diw[d*512 + 256 + tid];
            int nt = n >> 4, lr = n & 15;
            int kc32 = tid >> 5, lq = (tid >> 3) & 3, jj = tid & 7;
            ((_Float16*)(ws + WS_CW16))[(kc32*16 + nt)*512 + (lq*16 + lr)*8 + jj] = (_Float16)acc;
        } else {
            int p = r;
            float acc = 0.f;
            #pragma unroll 4
            for (int k = 0; k < DD; ++k) acc += rowv[k] * diw[tid*512 + k];
            ((float*)(ws + WS_BASE))[p*DD + tid] = acc + dib[tid] + emb_prompt[p*DD + tid];
        }
    } else {
        int base = (blk - 384) * 512;
        half2* wb = (half2*)(ws + WS_WB16);
        #pragma unroll
        for (int j = 0; j < 2; ++j) {
            int idx = base + j*256 + tid;      // 0..65535
            half2 h; h[0] = (_Float16)few[idx]; h[1] = (_Float16)feb[idx];
            wb[idx] = h;
        }
    }
}

// ============================ prep kernel 2 ============================
// base_logits[p][n] = sum_d base[p][d] * col_ln[n][d]
__global__ __launch_bounds__(256) void k_prep2(char* __restrict__ ws)
{
    __shared__ float bs[DD];
    int p = blockIdx.x, n = threadIdx.x;
    const float* base   = (const float*)(ws + WS_BASE);
    const float* col_ln = (const float*)(ws + WS_COL_LN);
    bs[n] = base[p*DD + n];
    __syncthreads();
    float acc = 0.f;
    #pragma unroll 4
    for (int d = 0; d < DD; ++d) acc += bs[d] * col_ln[n*DD + d];
    ((float*)(ws + WS_BLOG))[p*DD + n] = acc;
}

// ============================ main kernel ============================
// R18/R20 measured-best form (181.4 us total).
// 1 block = 1 batch (grid 1024, 1024 thr, 16 waves = 4/SIMD).
// Wave w: p-tile pt=w>>1 (16 rows), half h=w&1 (n-half in P1, d-half in P2).
// P1: CW once in LDS (128 KB); 64 ds_read_b128 + 64 K=32 MFMA per wave
//     (barrier-free). acc 8xf32x4 (32 AGPR), pfrag 32 VGPR.
// Softmax: exp with LOCAL half-max, ONE barrier, cross-half rescale folded
//     into the P-write (factor = e^{m_h-M} / Z).
// P (f16) -> LDS over dead CW region, XOR-swizzled. P2 K=16, xe dbuf.
__global__ __launch_bounds__(1024) void trompt_main(
    const float* __restrict__ x, const float* __restrict__ prev,
    const float* __restrict__ expand_w, const float* __restrict__ expand_b,
    const float* __restrict__ ln_emb_g, const float* __restrict__ ln_emb_b,
    const char* __restrict__ ws, float* __restrict__ out)
{
    extern __shared__ char smem[];
    float* x_s  = (float*)(smem);
    float* sm_m = (float*)(smem + 1024);
    float* sm_l = (float*)(smem + 2048);
    char*  cwP  = smem + LDS_CWP;        // CW (P1) then P (P2)
    char*  xe0  = smem + LDS_XE0;
    char*  xe1  = smem + LDS_XE1;

    const char*  cwbase = ws + WS_CW16;
    const half2* WB     = (const half2*)(ws + WS_WB16);

    int b = blockIdx.x;
    int tid = threadIdx.x;
    int w = tid >> 6, l = tid & 63, lq = l >> 4, lr = l & 15;
    int pt = w >> 1, h = w & 1;
    int p  = 16*pt + lr;
    int pswz = (p & 7) << 4;

    if (tid < 256) x_s[tid] = x[b*NCOLS + tid];

    // prev row -> f16 K=32 B-fragments (32 VGPRs). Issued FIRST (HBM).
    half8 pf[8];
    {
        const float* prow = prev + ((size_t)b*NP + p)*DD + 8*lq;
        #pragma unroll
        for (int kc = 0; kc < 8; ++kc) {
            f32x4 v0 = *(const f32x4*)(prow + 32*kc);
            f32x4 v1 = *(const f32x4*)(prow + 32*kc + 4);
            half8 hh;
            #pragma unroll
            for (int j = 0; j < 4; ++j) { hh[j] = (_Float16)v0[j]; hh[4+j] = (_Float16)v1[j]; }
            pf[kc] = hh;
        }
    }

    // C-init from base_logits: acc[a] <-> n-tile nt = 8h + a
    f32x4 acc[8];
    {
        const float* blrow = (const float*)(ws + WS_BLOG) + (size_t)p*DD + 4*lq;
        #pragma unroll
        for (int a = 0; a < 8; ++a) acc[a] = *(const f32x4*)(blrow + 16*(8*h + a));
    }

    // cooperative CW load: 1024 thr x 8 x 16B = 131072 B = 128 KB (L2-hot)
    #pragma unroll
    for (int i = 0; i < 8; ++i) {
        int u = tid + 1024*i;
        *(uint4*)(cwP + u*16) = *(const uint4*)(cwbase + u*16);
    }

    __syncthreads();                 // CW + x_s ready

    // ---- Phase 1: logits, barrier-free 64x(b128+MFMA32) stretch ----
    {
        const char* cwl = cwP + (size_t)(8*h)*1024 + l*16;
        #pragma unroll
        for (int kc = 0; kc < 8; ++kc) {
            const char* fb = cwl + (size_t)kc*16384;
            half8 bp = pf[kc];
            #pragma unroll
            for (int a = 0; a < 8; ++a)
                acc[a] = MFMA32(*(const half8*)(fb + a*1024), bp, acc[a]);
        }
    }

    // ---- softmax, single barrier: exp with LOCAL half-max ----
    float mh = -1e30f;
    #pragma unroll
    for (int a = 0; a < 8; ++a)
        #pragma unroll
        for (int r = 0; r < 4; ++r) mh = fmaxf(mh, acc[a][r]);
    mh = fmaxf(mh, __shfl_xor(mh, 16));
    mh = fmaxf(mh, __shfl_xor(mh, 32));

    float sh = 0.f;
    #pragma unroll
    for (int a = 0; a < 8; ++a)
        #pragma unroll
        for (int r = 0; r < 4; ++r) { float e = __expf(acc[a][r] - mh); acc[a][r] = e; sh += e; }
    sh += __shfl_xor(sh, 16);
    sh += __shfl_xor(sh, 32);

    if (lq == 0) { sm_m[h*128 + p] = mh; sm_l[h*128 + p] = sh; }
    __syncthreads();                 // publish (m,s); also: all CW reads done
    float mo = sm_m[(1 ^ h)*128 + p];
    float so = sm_l[(1 ^ h)*128 + p];
    float M  = fmaxf(mh, mo);
    float eh = __expf(mh - M), eo = __expf(mo - M);
    float fac = eh / (sh*eh + so*eo);

    // ---- write normalized P (f16) over dead CW region, swizzled ----
    #pragma unroll
    for (int a = 0; a < 8; ++a) {
        int nb = (8*h + a)*32 + lq*8;        // byte offset of n*2 within row
        half4 hh;
        #pragma unroll
        for (int r = 0; r < 4; ++r) hh[r] = (_Float16)(acc[a][r] * fac);
        *(half4*)(cwP + p*512 + (nb ^ pswz)) = hh;
    }

    // ---- Phase 2 prologue ----
    float gcc[4], bcc[4];
    #pragma unroll
    for (int cc = 0; cc < 4; ++cc) {
        gcc[cc] = ln_emb_g[l + 64*cc];
        bcc[cc] = ln_emb_b[l + 64*cc];
    }

    // xe chunk compute: 64 n-rows -> f16 K=16 fragment buffer; 4 rows/wave.
    int kc2w = w >> 2, lq2 = w & 3;
    auto compute_xe = [&](int c, char* xebuf) {
        float vj[4][4];
        #pragma unroll
        for (int j = 0; j < 4; ++j) {
            int n = c*64 + 16*kc2w + 4*lq2 + j;
            float xv = x_s[n];
            const half2* wbrow = WB + n*DD;
            float ss = 0.f, qq = 0.f;
            #pragma unroll
            for (int cc = 0; cc < 4; ++cc) {
                half2 pp = wbrow[l + 64*cc];
                float e = fmaf(xv, (float)pp[0], (float)pp[1]);
                e = e > 0.f ? e : 0.f;
                vj[j][cc] = e; ss += e; qq += e*e;
            }
            #pragma unroll
            for (int off = 32; off; off >>= 1) { ss += __shfl_xor(ss, off); qq += __shfl_xor(qq, off); }
            float mu = ss * (1.0f/DD);
            float rs = rsqrtf(qq*(1.0f/DD) - mu*mu + 1e-5f);
            #pragma unroll
            for (int cc = 0; cc < 4; ++cc)
                vj[j][cc] = (vj[j][cc]-mu)*rs*gcc[cc] + bcc[cc];
        }
        #pragma unroll
        for (int cc = 0; cc < 4; ++cc) {
            int dt = 4*cc + (l >> 4);
            half4 hh;
            #pragma unroll
            for (int j = 0; j < 4; ++j) hh[j] = (_Float16)vj[j][cc];
            *(half4*)(xebuf + (((kc2w*16 + dt)*64) + lq2*16 + lr)*8) = hh;
        }
    };

    compute_xe(0, xe0);

    f32x4 acc_v[8];                  // 16p x 128d: d = 128h + 16dtl + 4lq + r
    #pragma unroll
    for (int dtl = 0; dtl < 8; ++dtl) acc_v[dtl] = (f32x4){0.f,0.f,0.f,0.f};

    __syncthreads();                 // P + xe0 complete

    for (int c = 0; c < 4; ++c) {
        char* xec = (c & 1) ? xe1 : xe0;
        char* xen = (c & 1) ? xe0 : xe1;

        // P B-fragments for this chunk (ds_read, swizzled, ~2-way free)
        half4 bp[4];
        #pragma unroll
        for (int kc2 = 0; kc2 < 4; ++kc2)
            bp[kc2] = *(const half4*)(cwP + p*512 + ((c*128 + kc2*32 + lq*8) ^ pswz));

        if (c < 3) compute_xe(c+1, xen);

        const char* xel = xec + l*8;
        #pragma unroll
        for (int kc2 = 0; kc2 < 4; ++kc2) {
            const char* xb = xel + (size_t)(kc2*16 + 8*h)*512;
            half4 bpc = bp[kc2];
            #pragma unroll
            for (int dtl = 0; dtl < 8; ++dtl)
                acc_v[dtl] = MFMA16(*(const half4*)(xb + dtl*512), bpc, acc_v[dtl]);
        }

        if (c < 3) __syncthreads();  // xen complete; xec free to overwrite
    }

    // epilogue: out = V*sw + sb (P pre-normalized); d-half per wave
    {
        float sw = 1.0f + expand_w[p];
        float sb = expand_b[p];
        float* orow = out + ((size_t)b*NP + p)*DD + 128*h + 4*lq;
        #pragma unroll
        for (int dtl = 0; dtl < 8; ++dtl) {
            f32x4 v = acc_v[dtl];
            #pragma unroll
            for (int r = 0; r < 4; ++r) v[r] = v[r]*sw + sb;
            *(f32x4*)(orow + 16*dtl) = v;
        }
    }
}

// ============================ launcher ============================
extern "C" void kernel_launch(void* const* d_in, const int* in_sizes, int n_in,
                              void* d_out, int out_size, void* d_ws, size_t ws_size,
                              hipStream_t stream) {
    (void)in_sizes; (void)n_in; (void)out_size; (void)ws_size;
    const float* x           = (const float*)d_in[0];
    const float* prev        = (const float*)d_in[1];
    const float* few         = (const float*)d_in[2];
    const float* feb         = (const float*)d_in[3];
    const float* ln_emb_g    = (const float*)d_in[4];
    const float* ln_emb_b    = (const float*)d_in[5];
    const float* ln_col_g    = (const float*)d_in[6];
    const float* ln_col_b    = (const float*)d_in[7];
    const float* ln_prompt_g = (const float*)d_in[8];
    const float* ln_prompt_b = (const float*)d_in[9];
    const float* diw         = (const float*)d_in[10];
    const float* dib         = (const float*)d_in[11];
    const float* emb_column  = (const float*)d_in[12];
    const float* emb_prompt  = (const float*)d_in[13];
    const float* expand_w    = (const float*)d_in[14];
    const float* expand_b    = (const float*)d_in[15];
    char* ws = (char*)d_ws;
    float* out = (float*)d_out;

    k_prep1<<<512, 256, 0, stream>>>(emb_column, emb_prompt, ln_col_g, ln_col_b,
                                     ln_prompt_g, ln_prompt_b, few, feb,
                                     diw, dib, ws);
    k_prep2<<<128, 256, 0, stream>>>(ws);

    (void)hipFuncSetAttribute(reinterpret_cast<const void*>(trompt_main),
                              hipFuncAttributeMaxDynamicSharedMemorySize, SMEM_MAIN);
    trompt_main<<<1024, 1024, SMEM_MAIN, stream>>>(x, prev, expand_w, expand_b,
                                                   ln_emb_g, ln_emb_b, ws, out);
}